// Round 7
// baseline (2640.056 us; speedup 1.0000x reference)
//
#include <hip/hip_runtime.h>

#define N 4096
#define B 8
#define ITERS 10
#define T (ITERS * N)
#define NT 256          // 4 waves
#define E 16            // field elements per thread
#define WIN 1024
#define INFK 0xFFFFFFFFu
#define LIMIT 0x01000000u   // 1024<<14: max valid relative key span

// LDS-only barrier: inner-loop cross-wave traffic is LDS slots only ->
// lgkmcnt(0) suffices; in-flight global row loads stay in flight.
// Parity-buffered slots + 1 barrier/round is race-free.
__device__ __forceinline__ void lds_barrier() {
    asm volatile("s_waitcnt lgkmcnt(0)\n\ts_barrier" ::: "memory");
}

// Kernel 1: Z0[b][i] = sum_j W[i][j] * x[b][j], accumulated in double. (proven)
__global__ __launch_bounds__(256) void z0_gemv(const float* __restrict__ W,
                                               const float* __restrict__ x,
                                               double* __restrict__ Z0) {
    const int i = blockIdx.x;
    const int tid = threadIdx.x;
    const int lane = tid & 63;
    const int wid = tid >> 6;
    const float4* __restrict__ row = (const float4*)(W + (size_t)i * N);
    const float4* __restrict__ xv = (const float4*)x;

    double acc[B];
#pragma unroll
    for (int b = 0; b < B; ++b) acc[b] = 0.0;

#pragma unroll
    for (int it = 0; it < 4; ++it) {
        const int c = tid + 256 * it;
        const float4 w = row[c];
#pragma unroll
        for (int b = 0; b < B; ++b) {
            const float4 xb = xv[b * (N / 4) + c];
            acc[b] += (double)w.x * (double)xb.x + (double)w.y * (double)xb.y +
                      (double)w.z * (double)xb.z + (double)w.w * (double)xb.w;
        }
    }

#pragma unroll
    for (int off = 32; off > 0; off >>= 1) {
#pragma unroll
        for (int b = 0; b < B; ++b) acc[b] += __shfl_down(acc[b], off, 64);
    }

    __shared__ double red[4][B];
    if (lane == 0) {
#pragma unroll
        for (int b = 0; b < B; ++b) red[wid][b] = acc[b];
    }
    __syncthreads();
    if (tid < B)
        Z0[(size_t)tid * N + i] = red[0][tid] + red[1][tid] + red[2][tid] + red[3][tid];
}

__device__ __forceinline__ unsigned umin2(unsigned a, unsigned b) { return a < b ? a : b; }
__device__ __forceinline__ unsigned umin4(unsigned a, unsigned b, unsigned c, unsigned d) {
    return umin2(umin2(a, b), umin2(c, d));
}

template <int CTRL>
__device__ __forceinline__ unsigned dpp_min(unsigned v) {
    const int t = __builtin_amdgcn_update_dpp((int)v, (int)v, CTRL, 0xF, 0xF, false);
    return umin2(v, (unsigned)t);
}

// Full wave64 min via DPP; wave-uniform result via readlane(63). (proven)
__device__ __forceinline__ unsigned wave_min64(unsigned v) {
    v = dpp_min<0x111>(v);  // row_shr:1
    v = dpp_min<0x112>(v);  // row_shr:2
    v = dpp_min<0x114>(v);  // row_shr:4
    v = dpp_min<0x118>(v);  // row_shr:8
    v = dpp_min<0x142>(v);  // row_bcast:15
    v = dpp_min<0x143>(v);  // row_bcast:31
    return (unsigned)__builtin_amdgcn_readlane((int)v, 63);
}

// Load this thread's 16-column fragment of row i into registers.
__device__ __forceinline__ void fetch_row(const float* __restrict__ W, int i,
                                          int tid, float* wr) {
    const float4* __restrict__ rp = (const float4*)(W + (size_t)i * N) + 4 * tid;
    const float4 a = rp[0], c = rp[1], e = rp[2], f = rp[3];
    wr[0] = a.x;  wr[1] = a.y;  wr[2] = a.z;  wr[3] = a.w;
    wr[4] = c.x;  wr[5] = c.y;  wr[6] = c.z;  wr[7] = c.w;
    wr[8] = e.x;  wr[9] = e.y;  wr[10] = e.z; wr[11] = e.w;
    wr[12] = f.x; wr[13] = f.y; wr[14] = f.z; wr[15] = f.w;
}

// toggle y/sk of element ii (one owner thread)
#define FIXUP(ii)                                                         \
    do {                                                                  \
        if (tid == ((ii) >> 4)) {                                         \
            const int kk = (ii) & 15;                                     \
            _Pragma("unroll") for (int k = 0; k < E; ++k) if (k == kk) {  \
                ym[k] ^= 0x80000000u;                                     \
                sk[k] ^= 2u;                                              \
            }                                                             \
        }                                                                 \
    } while (0)

// Kernel 2: quad-commit rounds (k=4 generalization of the proven k=2 pair
// commit). Each round carries n in {0..4} candidates (flip1 is always the
// TRUE next winner; 2..4 speculative). Fused pass computes states 1..n with
// per-state scan-mins key_q (rel ck_q = pos_q+1); key_q doubles as the gap-q
// validity min: gv_q < ck_{q+1}-ck_q  <=>  interloper in (pos_q,pos_{q+1})
// OR i_{q+1} de-mismatched (its pre-applied fixup sign-inverts its entry;
// entries beyond pos_{q+1} have rel >= gspan, entries <= pos_q wrap huge).
// First failing gap q: flips 1..q stay committed; state_q recomputed
// bit-exactly from checkpoint zc=state1 via the identical fma chain; the
// interloper (if in the open gap) IS the true next winner -> solo round;
// if i_{q+1} de-mismatched -> scan-only round from ck_{q+1}.
// Candidates g1..g4 come from per-wave top-2 publish + exact 8-value merge;
// imperfect g3/g4 only lowers success rate, never correctness.
// ONE barrier per round. Key algebra unchanged from rounds 0-6.
__global__ __launch_bounds__(256, 1) void hop_seq(const float* __restrict__ W,
                                                  const float* __restrict__ x,
                                                  const int* __restrict__ perms,
                                                  const double* __restrict__ Z0,
                                                  float* __restrict__ out) {
    const int b = blockIdx.x;
    const int tid = threadIdx.x;
    const int wid = tid >> 6;
    const int lane = tid & 63;

    __shared__ int wpos[N];                          // 16 KB epoch-tagged inverse map
    __shared__ __align__(16) unsigned pub[2][5][4];  // [parity][slot m1,m2,v1,v2,v3][wave]

    // ---- register-resident field ----
    double zj[E], zc[E];
    unsigned ym[E];                // 0xFFFFFFFF if y>0 else 0x7FFFFFFF
    unsigned sk[E];
    {
        const double* __restrict__ zsrc = Z0 + (size_t)b * N + E * tid;
#pragma unroll
        for (int k = 0; k < E; ++k) zj[k] = zsrc[k];
        const float4* __restrict__ xs = (const float4*)(x + (size_t)b * N);
#pragma unroll
        for (int q = 0; q < 4; ++q) {
            const float4 xv = xs[4 * tid + q];
            ym[4 * q + 0] = (xv.x > 0.f) ? 0xFFFFFFFFu : 0x7FFFFFFFu;
            ym[4 * q + 1] = (xv.y > 0.f) ? 0xFFFFFFFFu : 0x7FFFFFFFu;
            ym[4 * q + 2] = (xv.z > 0.f) ? 0xFFFFFFFFu : 0x7FFFFFFFu;
            ym[4 * q + 3] = (xv.w > 0.f) ? 0xFFFFFFFFu : 0x7FFFFFFFu;
        }
    }
    // zero-init inverse map (stale-tag hazard: LDS undefined at start)
    {
        const int4 z4 = make_int4(0, 0, 0, 0);
#pragma unroll
        for (int q = 0; q < 4; ++q) ((int4*)wpos)[tid + 256 * q] = z4;
    }
    lds_barrier();

    const int* __restrict__ perm_b = perms + (size_t)b * T;
    unsigned r = 0;                // barrier parity counter

    for (int base = 0; base < T; base += WIN) {
        const int epoch = (base >> 10) + 1;
        // scatter inverse map (window = permutation slice, indices distinct)
        const int4 iv = ((const int4*)(perm_b + base))[tid];
        wpos[iv.x] = (epoch << 10) | (4 * tid + 0);
        wpos[iv.y] = (epoch << 10) | (4 * tid + 1);
        wpos[iv.z] = (epoch << 10) | (4 * tid + 2);
        wpos[iv.w] = (epoch << 10) | (4 * tid + 3);
        lds_barrier();
        // build static keys for the 16 owned elems
#pragma unroll
        for (int q = 0; q < 4; ++q) {
            const int4 wp = ((const int4*)wpos)[4 * tid + q];
            const int e0 = 4 * q;
            const unsigned i0 = (unsigned)(E * tid + e0);
            sk[e0 + 0] = ((wp.x >> 10) == epoch)
                ? (((unsigned)(wp.x & 1023) << 14) | ((i0 + 0) << 2) | ((ym[e0 + 0] >> 30) & 2u)) : INFK;
            sk[e0 + 1] = ((wp.y >> 10) == epoch)
                ? (((unsigned)(wp.y & 1023) << 14) | ((i0 + 1) << 2) | ((ym[e0 + 1] >> 30) & 2u)) : INFK;
            sk[e0 + 2] = ((wp.z >> 10) == epoch)
                ? (((unsigned)(wp.z & 1023) << 14) | ((i0 + 2) << 2) | ((ym[e0 + 2] >> 30) & 2u)) : INFK;
            sk[e0 + 3] = ((wp.w >> 10) == epoch)
                ? (((unsigned)(wp.w & 1023) << 14) | ((i0 + 3) << 2) | ((ym[e0 + 3] >> 30) & 2u)) : INFK;
        }

        unsigned n = 0;                         // candidates carried this round
        unsigned wk1 = 0, wk2 = 0, wk3 = 0, wk4 = 0;
        unsigned ckR = 0;                       // cursor for scan-only rounds
        float w1[E], w2[E], w3[E], w4[E];

        for (;;) {
            // ---- uniform decode + owner fixups ----
            unsigned ck1 = 0, ck2 = 0, ck3 = 0, ck4 = 0, ckP;
            int i1 = 0, i2 = 0, i3 = 0, i4 = 0;
            double d1 = 0.0, d2 = 0.0, d3 = 0.0, d4 = 0.0;
            if (n >= 1) {
                i1 = (int)((wk1 >> 2) & 4095u);
                d1 = (double)(-2 * ((int)(wk1 & 3u) - 1));
                ck1 = ((wk1 >> 14) + 1u) << 14;
                FIXUP(i1);
            }
            if (n >= 2) {
                i2 = (int)((wk2 >> 2) & 4095u);
                d2 = (double)(-2 * ((int)(wk2 & 3u) - 1));
                ck2 = ((wk2 >> 14) + 1u) << 14;
                FIXUP(i2);
            }
            if (n >= 3) {
                i3 = (int)((wk3 >> 2) & 4095u);
                d3 = (double)(-2 * ((int)(wk3 & 3u) - 1));
                ck3 = ((wk3 >> 14) + 1u) << 14;
                FIXUP(i3);
            }
            if (n >= 4) {
                i4 = (int)((wk4 >> 2) & 4095u);
                d4 = (double)(-2 * ((int)(wk4 & 3u) - 1));
                ck4 = ((wk4 >> 14) + 1u) << 14;
                FIXUP(i4);
            }
            ckP = (n == 0) ? ckR : (n == 1) ? ck1 : (n == 2) ? ck2 : (n == 3) ? ck3 : ck4;

            // ---- fused passes: states 1..n, per-state scan-mins ----
            unsigned key1 = INFK, key2 = INFK, key3 = INFK, keyP = INFK;
            if (n == 0) {
#pragma unroll
                for (int k = 0; k < E; ++k) {
                    const unsigned t = ((unsigned)__double2hiint(zj[k])) ^ ym[k];
                    keyP = umin2(keyP, (sk[k] | (unsigned)(((int)t) >> 31)) - ckR);
                }
            } else {
#pragma unroll
                for (int k = 0; k < E; ++k) {   // pass1 -> zc (checkpoint)
                    const double a = fma(d1, (double)w1[k], zj[k]);
                    zc[k] = a;
                    const unsigned t = ((unsigned)__double2hiint(a)) ^ ym[k];
                    key1 = umin2(key1, (sk[k] | (unsigned)(((int)t) >> 31)) - ck1);
                }
                if (n == 1) {
#pragma unroll
                    for (int k = 0; k < E; ++k) zj[k] = zc[k];
                    keyP = key1;
                }
                if (n >= 2) {
#pragma unroll
                    for (int k = 0; k < E; ++k) {   // pass2
                        const double c = fma(d2, (double)w2[k], zc[k]);
                        zj[k] = c;
                        const unsigned t = ((unsigned)__double2hiint(c)) ^ ym[k];
                        key2 = umin2(key2, (sk[k] | (unsigned)(((int)t) >> 31)) - ck2);
                    }
                    if (n == 2) keyP = key2;
                }
                if (n >= 3) {
#pragma unroll
                    for (int k = 0; k < E; ++k) {   // pass3
                        const double c = fma(d3, (double)w3[k], zj[k]);
                        zj[k] = c;
                        const unsigned t = ((unsigned)__double2hiint(c)) ^ ym[k];
                        key3 = umin2(key3, (sk[k] | (unsigned)(((int)t) >> 31)) - ck3);
                    }
                    if (n == 3) keyP = key3;
                }
                if (n >= 4) {
                    unsigned key4 = INFK;
#pragma unroll
                    for (int k = 0; k < E; ++k) {   // pass4
                        const double c = fma(d4, (double)w4[k], zj[k]);
                        zj[k] = c;
                        const unsigned t = ((unsigned)__double2hiint(c)) ^ ym[k];
                        key4 = umin2(key4, (sk[k] | (unsigned)(((int)t) >> 31)) - ck4);
                    }
                    keyP = key4;
                }
            }

            // ---- trees: post top-2 (serial pair) + validity mins (indep) ----
            const unsigned m1 = wave_min64(keyP);
            const unsigned mv1 = (n >= 2) ? wave_min64(key1) : INFK;
            const unsigned mv2 = (n >= 3) ? wave_min64(key2) : INFK;
            const unsigned mv3 = (n >= 4) ? wave_min64(key3) : INFK;
            const unsigned m2 = wave_min64(keyP == m1 ? INFK : keyP);

            // ---- publish 5 words/wave, ONE barrier ----
            unsigned pv = m1;
            pv = (lane == 1) ? m2 : pv;
            pv = (lane == 2) ? mv1 : pv;
            pv = (lane == 3) ? mv2 : pv;
            pv = (lane == 4) ? mv3 : pv;
            const unsigned p = r & 1u; ++r;
            if (lane < 5) pub[p][lane][wid] = pv;
            lds_barrier();

            const uint4 M1 = *(const uint4*)&pub[p][0][0];
            const uint4 M2 = *(const uint4*)&pub[p][1][0];

            // ---- validity resolution (ordered, first failing gap wins) ----
            if (n >= 2) {
                const uint4 V1 = *(const uint4*)&pub[p][2][0];
                const unsigned gv1 = umin4(V1.x, V1.y, V1.z, V1.w);
                if (gv1 < ck2 - ck1) {
                    // fail gap1: state = state1 (= zc); revert fixups 2..n
#pragma unroll
                    for (int k = 0; k < E; ++k) zj[k] = zc[k];
                    FIXUP(i2);
                    if (n >= 3) FIXUP(i3);
                    if (n >= 4) FIXUP(i4);
                    const unsigned vabs = gv1 + ck1;
                    if ((vabs >> 14) == (wk2 >> 14)) { n = 0; ckR = ck2; }
                    else { wk1 = vabs; n = 1; fetch_row(W, (int)((vabs >> 2) & 4095u), tid, w1); }
                    continue;
                }
            }
            if (n >= 3) {
                const uint4 V2 = *(const uint4*)&pub[p][3][0];
                const unsigned gv2 = umin4(V2.x, V2.y, V2.z, V2.w);
                if (gv2 < ck3 - ck2) {
                    // fail gap2: state2 = fma(d2,w2,zc) (bit-exact recompute)
#pragma unroll
                    for (int k = 0; k < E; ++k) zj[k] = fma(d2, (double)w2[k], zc[k]);
                    FIXUP(i3);
                    if (n >= 4) FIXUP(i4);
                    const unsigned vabs = gv2 + ck2;
                    if ((vabs >> 14) == (wk3 >> 14)) { n = 0; ckR = ck3; }
                    else { wk1 = vabs; n = 1; fetch_row(W, (int)((vabs >> 2) & 4095u), tid, w1); }
                    continue;
                }
            }
            if (n >= 4) {
                const uint4 V3 = *(const uint4*)&pub[p][4][0];
                const unsigned gv3 = umin4(V3.x, V3.y, V3.z, V3.w);
                if (gv3 < ck4 - ck3) {
                    // fail gap3: state3 = fma(d3,w3,fma(d2,w2,zc))
#pragma unroll
                    for (int k = 0; k < E; ++k)
                        zj[k] = fma(d3, (double)w3[k], fma(d2, (double)w2[k], zc[k]));
                    FIXUP(i4);
                    const unsigned vabs = gv3 + ck3;
                    if ((vabs >> 14) == (wk4 >> 14)) { n = 0; ckR = ck4; }
                    else { wk1 = vabs; n = 1; fetch_row(W, (int)((vabs >> 2) & 4095u), tid, w1); }
                    continue;
                }
            }

            // ---- SUCCESS: exact 8-value merge -> global top-4 candidates ----
            unsigned h0 = M1.x, h1 = M1.y, h2 = M1.z, h3 = M1.w;
            unsigned x0 = M2.x, x1 = M2.y, x2 = M2.z, x3 = M2.w;
            const unsigned g1 = umin4(h0, h1, h2, h3);
            if (g1 >= LIMIT) break;        // window converged (state stands)
            {
                const bool c0 = (h0 == g1), c1 = (h1 == g1), c2 = (h2 == g1), c3 = (h3 == g1);
                h0 = c0 ? x0 : h0; x0 = c0 ? INFK : x0;
                h1 = c1 ? x1 : h1; x1 = c1 ? INFK : x1;
                h2 = c2 ? x2 : h2; x2 = c2 ? INFK : x2;
                h3 = c3 ? x3 : h3; x3 = c3 ? INFK : x3;
            }
            const unsigned g2 = umin4(h0, h1, h2, h3);
            {
                const bool c0 = (h0 == g2), c1 = (h1 == g2), c2 = (h2 == g2), c3 = (h3 == g2);
                h0 = c0 ? x0 : h0; x0 = c0 ? INFK : x0;
                h1 = c1 ? x1 : h1; x1 = c1 ? INFK : x1;
                h2 = c2 ? x2 : h2; x2 = c2 ? INFK : x2;
                h3 = c3 ? x3 : h3; x3 = c3 ? INFK : x3;
            }
            const unsigned g3 = umin4(h0, h1, h2, h3);
            {
                const bool c0 = (h0 == g3), c1 = (h1 == g3), c2 = (h2 == g3), c3 = (h3 == g3);
                h0 = c0 ? x0 : h0;
                h1 = c1 ? x1 : h1;
                h2 = c2 ? x2 : h2;
                h3 = c3 ? x3 : h3;
            }
            const unsigned g4 = umin4(h0, h1, h2, h3);

            wk1 = g1 + ckP; n = 1;
            fetch_row(W, (int)((wk1 >> 2) & 4095u), tid, w1);
            if (g2 < LIMIT) {
                wk2 = g2 + ckP; n = 2;
                fetch_row(W, (int)((wk2 >> 2) & 4095u), tid, w2);
                if (g3 < LIMIT) {
                    wk3 = g3 + ckP; n = 3;
                    fetch_row(W, (int)((wk3 >> 2) & 4095u), tid, w3);
                    if (g4 < LIMIT) {
                        wk4 = g4 + ckP; n = 4;
                        fetch_row(W, (int)((wk4 >> 2) & 4095u), tid, w4);
                    }
                }
            }
        }
    }

    // ---- output: y = +1 if ym top bit set else -1 ----
    float4* __restrict__ os = (float4*)(out + (size_t)b * N);
#pragma unroll
    for (int q = 0; q < 4; ++q) {
        float4 o;
        o.x = (ym[4 * q + 0] & 0x80000000u) ? 1.0f : -1.0f;
        o.y = (ym[4 * q + 1] & 0x80000000u) ? 1.0f : -1.0f;
        o.z = (ym[4 * q + 2] & 0x80000000u) ? 1.0f : -1.0f;
        o.w = (ym[4 * q + 3] & 0x80000000u) ? 1.0f : -1.0f;
        os[4 * tid + q] = o;
    }
}

extern "C" void kernel_launch(void* const* d_in, const int* in_sizes, int n_in,
                              void* d_out, int out_size, void* d_ws, size_t ws_size,
                              hipStream_t stream) {
    const float* x = (const float*)d_in[0];      // [B, N] f32, bipolar
    const float* W = (const float*)d_in[1];      // [N, N] f32, symmetric, zero diag
    const int* perms = (const int*)d_in[2];      // [B, ITERS, N] i32
    float* out = (float*)d_out;                  // [B, N] f32
    double* Z0 = (double*)d_ws;                  // B*N doubles = 256 KB scratch

    hipLaunchKernelGGL(z0_gemv, dim3(N), dim3(256), 0, stream, W, x, Z0);
    hipLaunchKernelGGL(hop_seq, dim3(B), dim3(NT), 0, stream, W, x, perms, Z0, out);
}

// Round 8
// 2216.258 us; speedup vs baseline: 1.1912x; 1.1912x over previous
//
#include <hip/hip_runtime.h>

#define N 4096
#define B 8
#define ITERS 10
#define T (ITERS * N)
#define NT 256          // 4 waves
#define E 16            // field elements per thread
#define WIN 1024
#define INFK 0xFFFFFFFFu
#define LIMIT 0x01000000u   // 1024<<14: max valid relative key span

// LDS-only barrier: inner-loop cross-wave traffic is LDS slots only ->
// lgkmcnt(0) suffices; in-flight global row loads stay in flight.
// Parity-buffered slots + 1 barrier/round is race-free.
__device__ __forceinline__ void lds_barrier() {
    asm volatile("s_waitcnt lgkmcnt(0)\n\ts_barrier" ::: "memory");
}

// Kernel 1: Z0[b][i] = sum_j W[i][j] * x[b][j], double accumulation.
// 2 rows per block: halves the x re-read traffic (x shared across both rows).
__global__ __launch_bounds__(256) void z0_gemv(const float* __restrict__ W,
                                               const float* __restrict__ x,
                                               double* __restrict__ Z0) {
    const int i0 = 2 * blockIdx.x;
    const int tid = threadIdx.x;
    const int lane = tid & 63;
    const int wid = tid >> 6;
    const float4* __restrict__ row0 = (const float4*)(W + (size_t)i0 * N);
    const float4* __restrict__ row1 = (const float4*)(W + (size_t)(i0 + 1) * N);
    const float4* __restrict__ xv = (const float4*)x;

    double acc0[B], acc1[B];
#pragma unroll
    for (int b = 0; b < B; ++b) { acc0[b] = 0.0; acc1[b] = 0.0; }

#pragma unroll
    for (int it = 0; it < 4; ++it) {
        const int c = tid + 256 * it;
        const float4 w0 = row0[c];
        const float4 w1 = row1[c];
#pragma unroll
        for (int b = 0; b < B; ++b) {
            const float4 xb = xv[b * (N / 4) + c];
            acc0[b] += (double)w0.x * (double)xb.x + (double)w0.y * (double)xb.y +
                       (double)w0.z * (double)xb.z + (double)w0.w * (double)xb.w;
            acc1[b] += (double)w1.x * (double)xb.x + (double)w1.y * (double)xb.y +
                       (double)w1.z * (double)xb.z + (double)w1.w * (double)xb.w;
        }
    }

#pragma unroll
    for (int off = 32; off > 0; off >>= 1) {
#pragma unroll
        for (int b = 0; b < B; ++b) {
            acc0[b] += __shfl_down(acc0[b], off, 64);
            acc1[b] += __shfl_down(acc1[b], off, 64);
        }
    }

    __shared__ double red[4][2][B];
    if (lane == 0) {
#pragma unroll
        for (int b = 0; b < B; ++b) { red[wid][0][b] = acc0[b]; red[wid][1][b] = acc1[b]; }
    }
    __syncthreads();
    if (tid < B) {
        Z0[(size_t)tid * N + i0] =
            red[0][0][tid] + red[1][0][tid] + red[2][0][tid] + red[3][0][tid];
        Z0[(size_t)tid * N + i0 + 1] =
            red[0][1][tid] + red[1][1][tid] + red[2][1][tid] + red[3][1][tid];
    }
}

__device__ __forceinline__ unsigned umin2(unsigned a, unsigned b) { return a < b ? a : b; }
__device__ __forceinline__ unsigned umin4(unsigned a, unsigned b, unsigned c, unsigned d) {
    return umin2(umin2(a, b), umin2(c, d));
}

template <int CTRL>
__device__ __forceinline__ unsigned dpp_min(unsigned v) {
    const int t = __builtin_amdgcn_update_dpp((int)v, (int)v, CTRL, 0xF, 0xF, false);
    return umin2(v, (unsigned)t);
}

// 4-step row-min: lane i = min over its 16-lane group; lanes 15/31/47/63
// hold the four quarter-mins of the wave.
__device__ __forceinline__ unsigned quarter_min(unsigned v) {
    v = dpp_min<0x111>(v);  // row_shr:1
    v = dpp_min<0x112>(v);  // row_shr:2
    v = dpp_min<0x114>(v);  // row_shr:4
    v = dpp_min<0x118>(v);  // row_shr:8
    return v;
}

// Full-wave min (6 steps); valid in lane 63.
__device__ __forceinline__ unsigned full_min(unsigned v) {
    v = quarter_min(v);
    v = dpp_min<0x142>(v);  // row_bcast:15
    v = dpp_min<0x143>(v);  // row_bcast:31
    return v;
}

// Load this thread's 16-column fragment of row i into registers.
__device__ __forceinline__ void fetch_row(const float* __restrict__ W, int i,
                                          int tid, float* wr) {
    const float4* __restrict__ rp = (const float4*)(W + (size_t)i * N) + 4 * tid;
    const float4 a = rp[0], c = rp[1], e = rp[2], f = rp[3];
    wr[0] = a.x;  wr[1] = a.y;  wr[2] = a.z;  wr[3] = a.w;
    wr[4] = c.x;  wr[5] = c.y;  wr[6] = c.z;  wr[7] = c.w;
    wr[8] = e.x;  wr[9] = e.y;  wr[10] = e.z; wr[11] = e.w;
    wr[12] = f.x; wr[13] = f.y; wr[14] = f.z; wr[15] = f.w;
}

// toggle y/sk of element ii (one owner thread)
#define FIXUP(ii)                                                         \
    do {                                                                  \
        if (tid == ((ii) >> 4)) {                                         \
            const int kk = (ii) & 15;                                     \
            _Pragma("unroll") for (int k = 0; k < E; ++k) if (k == kk) {  \
                ym[k] ^= 0x80000000u;                                     \
                sk[k] ^= 2u;                                              \
            }                                                             \
        }                                                                 \
    } while (0)

// Kernel 2: pair-commit rounds (proven k=2 structure, round 6) with
//  (a) quarter-min publish: 16 group-mins replace the serial m1->m2 DPP
//      chains; g1 exact, g2 = exact 2nd-of-16 (speculative quality only),
//  (b) w1 fetched immediately after g1 (before g2 merge / validity),
//  (c) interloper failure keeps the old (wk2, w2) pair -> failed rounds
//      still enter the next round with a 2-commit candidate pair.
// Validity semantics unchanged: key1 (mid-scan min, rel ck1) doubles as the
// gap-validity min; success <=> gv >= ck2-ck1. i2's fixup is pre-applied so
// its entry is sign-inverted (contributes only on de-mismatch).
// Exactness: success z = fma(d2,w2,fma(d1,w1,z)); failure z = zc (bit-exact
// single apply). Identical op order to the sequential reference.
__global__ __launch_bounds__(256, 1) void hop_seq(const float* __restrict__ W,
                                                  const float* __restrict__ x,
                                                  const int* __restrict__ perms,
                                                  const double* __restrict__ Z0,
                                                  float* __restrict__ out) {
    const int b = blockIdx.x;
    const int tid = threadIdx.x;
    const int wid = tid >> 6;
    const int lane = tid & 63;

    __shared__ int wpos[N];                         // 16 KB epoch-tagged inverse map
    __shared__ __align__(16) unsigned pubP[2][16];  // 4 quarter-mins x 4 waves, parity
    __shared__ __align__(16) unsigned pubV[2][4];   // validity min per wave, parity

    // ---- register-resident field ----
    double zj[E], zc[E];
    unsigned ym[E];                // 0xFFFFFFFF if y>0 else 0x7FFFFFFF
    unsigned sk[E];
    {
        const double* __restrict__ zsrc = Z0 + (size_t)b * N + E * tid;
#pragma unroll
        for (int k = 0; k < E; ++k) zj[k] = zsrc[k];
        const float4* __restrict__ xs = (const float4*)(x + (size_t)b * N);
#pragma unroll
        for (int q = 0; q < 4; ++q) {
            const float4 xv = xs[4 * tid + q];
            ym[4 * q + 0] = (xv.x > 0.f) ? 0xFFFFFFFFu : 0x7FFFFFFFu;
            ym[4 * q + 1] = (xv.y > 0.f) ? 0xFFFFFFFFu : 0x7FFFFFFFu;
            ym[4 * q + 2] = (xv.z > 0.f) ? 0xFFFFFFFFu : 0x7FFFFFFFu;
            ym[4 * q + 3] = (xv.w > 0.f) ? 0xFFFFFFFFu : 0x7FFFFFFFu;
        }
    }
    // zero-init inverse map (stale-tag hazard: LDS undefined at start)
    {
        const int4 z4 = make_int4(0, 0, 0, 0);
#pragma unroll
        for (int q = 0; q < 4; ++q) ((int4*)wpos)[tid + 256 * q] = z4;
    }
    lds_barrier();

    const int* __restrict__ perm_b = perms + (size_t)b * T;
    unsigned r = 0;                // barrier parity counter

    for (int base = 0; base < T; base += WIN) {
        const int epoch = (base >> 10) + 1;
        // scatter inverse map (window = permutation slice, indices distinct)
        const int4 iv = ((const int4*)(perm_b + base))[tid];
        wpos[iv.x] = (epoch << 10) | (4 * tid + 0);
        wpos[iv.y] = (epoch << 10) | (4 * tid + 1);
        wpos[iv.z] = (epoch << 10) | (4 * tid + 2);
        wpos[iv.w] = (epoch << 10) | (4 * tid + 3);
        lds_barrier();
        // build static keys for the 16 owned elems
#pragma unroll
        for (int q = 0; q < 4; ++q) {
            const int4 wp = ((const int4*)wpos)[4 * tid + q];
            const int e0 = 4 * q;
            const unsigned i0 = (unsigned)(E * tid + e0);
            sk[e0 + 0] = ((wp.x >> 10) == epoch)
                ? (((unsigned)(wp.x & 1023) << 14) | ((i0 + 0) << 2) | ((ym[e0 + 0] >> 30) & 2u)) : INFK;
            sk[e0 + 1] = ((wp.y >> 10) == epoch)
                ? (((unsigned)(wp.y & 1023) << 14) | ((i0 + 1) << 2) | ((ym[e0 + 1] >> 30) & 2u)) : INFK;
            sk[e0 + 2] = ((wp.z >> 10) == epoch)
                ? (((unsigned)(wp.z & 1023) << 14) | ((i0 + 2) << 2) | ((ym[e0 + 2] >> 30) & 2u)) : INFK;
            sk[e0 + 3] = ((wp.w >> 10) == epoch)
                ? (((unsigned)(wp.w & 1023) << 14) | ((i0 + 3) << 2) | ((ym[e0 + 3] >> 30) & 2u)) : INFK;
        }

        unsigned n = 0;                  // candidates carried this round (0/1/2)
        unsigned wk1 = 0, wk2 = 0;       // absolute keys of the pair
        unsigned ckR = 0;                // cursor for scan-only rounds
        float w1[E], w2[E];

        for (;;) {
            // ---- uniform decode + owner fixups ----
            unsigned ck1 = 0, ck2 = 0, ckP;
            int i1 = 0, i2 = 0;
            double d1 = 0.0, d2 = 0.0;
            if (n >= 1) {
                i1 = (int)((wk1 >> 2) & 4095u);
                d1 = (double)(-2 * ((int)(wk1 & 3u) - 1));
                ck1 = ((wk1 >> 14) + 1u) << 14;
                FIXUP(i1);
            }
            if (n == 2) {
                i2 = (int)((wk2 >> 2) & 4095u);
                d2 = (double)(-2 * ((int)(wk2 & 3u) - 1));
                ck2 = ((wk2 >> 14) + 1u) << 14;
                FIXUP(i2);
            }
            ckP = (n == 0) ? ckR : (n == 1) ? ck1 : ck2;

            // ---- fused pass: states + scan mins ----
            unsigned key1 = INFK, keyP = INFK;
            if (n == 2) {
#pragma unroll
                for (int k = 0; k < E; ++k) {
                    const double a = fma(d1, (double)w1[k], zj[k]);   // mid
                    zc[k] = a;
                    const unsigned tm = ((unsigned)__double2hiint(a)) ^ ym[k];
                    key1 = umin2(key1, (sk[k] | (unsigned)(((int)tm) >> 31)) - ck1);
                    const double c = fma(d2, (double)w2[k], a);       // post
                    zj[k] = c;
                    const unsigned tp = ((unsigned)__double2hiint(c)) ^ ym[k];
                    keyP = umin2(keyP, (sk[k] | (unsigned)(((int)tp) >> 31)) - ck2);
                }
            } else if (n == 1) {
#pragma unroll
                for (int k = 0; k < E; ++k) {
                    const double c = fma(d1, (double)w1[k], zj[k]);
                    zj[k] = c;
                    const unsigned tp = ((unsigned)__double2hiint(c)) ^ ym[k];
                    keyP = umin2(keyP, (sk[k] | (unsigned)(((int)tp) >> 31)) - ck1);
                }
            } else {
#pragma unroll
                for (int k = 0; k < E; ++k) {
                    const unsigned tp = ((unsigned)__double2hiint(zj[k])) ^ ym[k];
                    keyP = umin2(keyP, (sk[k] | (unsigned)(((int)tp) >> 31)) - ckR);
                }
            }

            // ---- trees: 4-step quarter chain (P) + 6-step full chain (V) ----
            const unsigned vP = quarter_min(keyP);
            const unsigned vV = full_min(key1);   // INFK when n<2

            // ---- publish (no readlane: lanes 15/31/47/63 write directly) ----
            const unsigned p = r & 1u; ++r;
            if ((lane & 15) == 15) pubP[p][4 * wid + (lane >> 4)] = vP;
            if (lane == 63) pubV[p][wid] = vV;
            lds_barrier();

            // ---- g1 (exact) + early w1 fetch ----
            const uint4 q0 = *(const uint4*)&pubP[p][0];
            const uint4 q1 = *(const uint4*)&pubP[p][4];
            const uint4 q2 = *(const uint4*)&pubP[p][8];
            const uint4 q3 = *(const uint4*)&pubP[p][12];
            const unsigned g1 = umin2(umin2(umin4(q0.x, q0.y, q0.z, q0.w),
                                            umin4(q1.x, q1.y, q1.z, q1.w)),
                                      umin2(umin4(q2.x, q2.y, q2.z, q2.w),
                                            umin4(q3.x, q3.y, q3.z, q3.w)));
            if (g1 < LIMIT)   // speculative: wasted only on validity failure
                fetch_row(W, (int)(((g1 + ckP) >> 2) & 4095u), tid, w1);

            // ---- g2: exact 2nd among the 16 group-mins ----
            const unsigned a00 = (q0.x == g1) ? INFK : q0.x;
            const unsigned a01 = (q0.y == g1) ? INFK : q0.y;
            const unsigned a02 = (q0.z == g1) ? INFK : q0.z;
            const unsigned a03 = (q0.w == g1) ? INFK : q0.w;
            const unsigned a10 = (q1.x == g1) ? INFK : q1.x;
            const unsigned a11 = (q1.y == g1) ? INFK : q1.y;
            const unsigned a12 = (q1.z == g1) ? INFK : q1.z;
            const unsigned a13 = (q1.w == g1) ? INFK : q1.w;
            const unsigned a20 = (q2.x == g1) ? INFK : q2.x;
            const unsigned a21 = (q2.y == g1) ? INFK : q2.y;
            const unsigned a22 = (q2.z == g1) ? INFK : q2.z;
            const unsigned a23 = (q2.w == g1) ? INFK : q2.w;
            const unsigned a30 = (q3.x == g1) ? INFK : q3.x;
            const unsigned a31 = (q3.y == g1) ? INFK : q3.y;
            const unsigned a32 = (q3.z == g1) ? INFK : q3.z;
            const unsigned a33 = (q3.w == g1) ? INFK : q3.w;
            const unsigned g2 = umin2(umin2(umin4(a00, a01, a02, a03),
                                            umin4(a10, a11, a12, a13)),
                                      umin2(umin4(a20, a21, a22, a23),
                                            umin4(a30, a31, a32, a33)));

            // ---- validity resolution (n==2 only) ----
            if (n == 2) {
                const uint4 vv = *(const uint4*)&pubV[p][0];
                const unsigned gv = umin4(vv.x, vv.y, vv.z, vv.w);
                if (gv < ck2 - ck1) {
                    // FAILURE: i1 stays committed; rollback to mid, revert i2
#pragma unroll
                    for (int k = 0; k < E; ++k) zj[k] = zc[k];
                    FIXUP(i2);
                    const unsigned vabs = gv + ck1;
                    if ((vabs >> 14) == (wk2 >> 14)) {
                        // i2 de-mismatched at mid: fresh scan from its cursor
                        n = 0; ckR = ck2;
                    } else {
                        // interloper = true next winner; KEEP old (wk2, w2)
                        // as the second candidate -> n stays 2.
                        wk1 = vabs;
                        fetch_row(W, (int)((vabs >> 2) & 4095u), tid, w1);
                    }
                    continue;
                }
            }

            // ---- SUCCESS / advance ----
            if (g1 >= LIMIT) break;        // window converged (state stands)
            wk1 = g1 + ckP; n = 1;         // w1 already fetched above
            if (g2 < LIMIT) {
                wk2 = g2 + ckP; n = 2;
                fetch_row(W, (int)((wk2 >> 2) & 4095u), tid, w2);
            }
        }
    }

    // ---- output: y = +1 if ym top bit set else -1 ----
    float4* __restrict__ os = (float4*)(out + (size_t)b * N);
#pragma unroll
    for (int q = 0; q < 4; ++q) {
        float4 o;
        o.x = (ym[4 * q + 0] & 0x80000000u) ? 1.0f : -1.0f;
        o.y = (ym[4 * q + 1] & 0x80000000u) ? 1.0f : -1.0f;
        o.z = (ym[4 * q + 2] & 0x80000000u) ? 1.0f : -1.0f;
        o.w = (ym[4 * q + 3] & 0x80000000u) ? 1.0f : -1.0f;
        os[4 * tid + q] = o;
    }
}

extern "C" void kernel_launch(void* const* d_in, const int* in_sizes, int n_in,
                              void* d_out, int out_size, void* d_ws, size_t ws_size,
                              hipStream_t stream) {
    const float* x = (const float*)d_in[0];      // [B, N] f32, bipolar
    const float* W = (const float*)d_in[1];      // [N, N] f32, symmetric, zero diag
    const int* perms = (const int*)d_in[2];      // [B, ITERS, N] i32
    float* out = (float*)d_out;                  // [B, N] f32
    double* Z0 = (double*)d_ws;                  // B*N doubles = 256 KB scratch

    hipLaunchKernelGGL(z0_gemv, dim3(N / 2), dim3(256), 0, stream, W, x, Z0);
    hipLaunchKernelGGL(hop_seq, dim3(B), dim3(NT), 0, stream, W, x, perms, Z0, out);
}